// Round 7
// baseline (136.041 us; speedup 1.0000x reference)
//
#include <hip/hip_runtime.h>

typedef __attribute__((ext_vector_type(8))) __bf16 bf16x8;
typedef __attribute__((ext_vector_type(4))) float f32x4;
typedef __attribute__((ext_vector_type(16))) float f32x16;
typedef __attribute__((ext_vector_type(4))) int i32x4;

#define GRID 1024
#define BLOCK 512
#define ITERS 4   // 8 batch rows per iter -> 32 rows per block

__device__ __forceinline__ int swzi(int row, int col) {
    return row * 128 + (col ^ ((row & 7) << 3));
}
__device__ __forceinline__ int cvt_pk_bf16(float lo, float hi) {
    int r; asm("v_cvt_pk_bf16_f32 %0, %1, %2" : "=v"(r) : "v"(lo), "v"(hi)); return r;
}
__device__ __forceinline__ void pl32swap(int& a, int& b) {
    asm("v_permlane32_swap_b32 %0, %1" : "+v"(a), "+v"(b));
}
__device__ __forceinline__ void pl32swapf(float& a, float& b) {
    asm("v_permlane32_swap_b32 %0, %1" : "+v"(a), "+v"(b));
}
__device__ __forceinline__ float bflo(unsigned u) {
    unsigned v = u << 16; return __builtin_bit_cast(float, v);
}
__device__ __forceinline__ float bfhi(unsigned u) {
    unsigned v = u & 0xffff0000u; return __builtin_bit_cast(float, v);
}

// ws layout (bytes):
//   0     : W1p bf16 [128][16]  (k<15: W1, k==15: b1 bias-fold)
//   4096  : W2p bf16 [128][128] swzi-swizzled (row=out e, col=in d)
//   36864 : W3p bf16 [128][128] swzi-swizzled
//   69632 : Mp  bf16 [128][128] row-major, M[d][f] = sum_e Ur[e][d]*Uq[e][f]
__global__ __launch_bounds__(128)
void pack_kernel(const float* __restrict__ W1, const float* __restrict__ b1,
                 const float* __restrict__ W2, const float* __restrict__ W3,
                 const float* __restrict__ Uq, const float* __restrict__ Ur,
                 unsigned char* __restrict__ ws)
{
    __bf16* w1p = (__bf16*)ws;
    __bf16* w2p = (__bf16*)(ws + 4096);
    __bf16* w3p = (__bf16*)(ws + 36864);
    __bf16* mp  = (__bf16*)(ws + 69632);
    const int d = blockIdx.x, t = threadIdx.x;
    if (t < 16) w1p[d * 16 + t] = (__bf16)((t < 15) ? W1[d * 15 + t] : b1[d]);
    w2p[swzi(d, t)] = (__bf16)W2[d * 128 + t];
    w3p[swzi(d, t)] = (__bf16)W3[d * 128 + t];
    float acc = 0.f;
    for (int e = 0; e < 128; ++e)
        acc = fmaf(Ur[e * 128 + d], Uq[e * 128 + t], acc);
    mp[d * 128 + t] = (__bf16)acc;
}

__global__ __launch_bounds__(BLOCK, 2)
void fused_attn_kernel(const float* __restrict__ obs,
                       const float* __restrict__ b2g, const float* __restrict__ b3g,
                       const unsigned char* __restrict__ ws,
                       float* __restrict__ out)
{
    const __bf16* gW1 = (const __bf16*)ws;
    const __bf16* gW2 = (const __bf16*)(ws + 4096);
    const __bf16* gW3 = (const __bf16*)(ws + 36864);
    const __bf16* gM  = (const __bf16*)(ws + 69632);

    __shared__ __align__(16) __bf16 sW2[128 * 128];
    __shared__ __align__(16) __bf16 sW3[128 * 128];
    __shared__ __align__(16) __bf16 sX[256 * 128];   // x_real: 8 rows x 32 objs
    __shared__ __align__(16) __bf16 sQ[16 * 128];    // q padded to 16 rows
    __shared__ __align__(16) float sV[8 * 128];
    __shared__ __align__(16) float sB2[128], sB3[128];

    const int tid = threadIdx.x, lane = tid & 63, wv = tid >> 6;
    const int l31 = lane & 31, hi = lane >> 5;
    const int l15 = lane & 15, kh = lane >> 4;

    // ---- one-time staging ----
    for (int i = tid * 8; i < 128 * 128; i += BLOCK * 8) {
        *(bf16x8*)&sW2[i] = *(const bf16x8*)&gW2[i];
        *(bf16x8*)&sW3[i] = *(const bf16x8*)&gW3[i];
    }
    for (int i = tid; i < 16 * 128; i += BLOCK) sQ[i] = (__bf16)0.f;
    if (tid < 128) { sB2[tid] = b2g[tid]; sB3[tid] = b3g[tid]; }

    bf16x8 w1f[4];
    #pragma unroll
    for (int m = 0; m < 4; ++m)
        w1f[m] = *(const bf16x8*)&gW1[(m * 32 + l31) * 16 + hi * 8];
    bf16x8 mf[4];
    #pragma unroll
    for (int kk = 0; kk < 4; ++kk)
        mf[kk] = *(const bf16x8*)&gM[(wv * 16 + l15) * 128 + kk * 32 + kh * 8];
    __syncthreads();

    // transposed layer via 32x32x16: dst[e][n] = bias[e] + sum_d Ws[e][d]*src[d][n]
    // bias loaded as accumulator init; A-frags double-buffered in regs.
    auto layer32 = [&](const f32x16 (&src)[4], f32x16 (&dst)[4],
                       const __bf16* Ws, const float* sB, bool do_relu) {
        #pragma unroll
        for (int m = 0; m < 4; ++m)
            #pragma unroll
            for (int rg = 0; rg < 4; ++rg) {
                f32x4 bb = *(const f32x4*)&sB[m * 32 + rg * 8 + hi * 4];
                dst[m][rg * 4 + 0] = bb.x; dst[m][rg * 4 + 1] = bb.y;
                dst[m][rg * 4 + 2] = bb.z; dst[m][rg * 4 + 3] = bb.w;
            }
        bf16x8 af[4];
        #pragma unroll
        for (int m = 0; m < 4; ++m) {
            int row = m * 32 + l31;
            af[m] = *(const bf16x8*)&Ws[row * 128 + ((hi * 8) ^ ((row & 7) << 3))];
        }
        #pragma unroll
        for (int kt = 0; kt < 8; ++kt) {
            bf16x8 afn[4];
            if (kt < 7) {
                #pragma unroll
                for (int m = 0; m < 4; ++m) {
                    int row = m * 32 + l31;
                    afn[m] = *(const bf16x8*)&Ws[row * 128 + (((kt + 1) * 16 + hi * 8) ^ ((row & 7) << 3))];
                }
            }
            const int ms = kt >> 1, b0 = (kt & 1) * 8;
            int Pa0 = cvt_pk_bf16(src[ms][b0 + 0], src[ms][b0 + 1]);
            int Pb0 = cvt_pk_bf16(src[ms][b0 + 2], src[ms][b0 + 3]);
            int Pa1 = cvt_pk_bf16(src[ms][b0 + 4], src[ms][b0 + 5]);
            int Pb1 = cvt_pk_bf16(src[ms][b0 + 6], src[ms][b0 + 7]);
            pl32swap(Pa0, Pa1);
            pl32swap(Pb0, Pb1);
            i32x4 wi; wi.x = Pa0; wi.y = Pb0; wi.z = Pa1; wi.w = Pb1;
            bf16x8 bfr = __builtin_bit_cast(bf16x8, wi);
            __builtin_amdgcn_s_setprio(1);
            #pragma unroll
            for (int m = 0; m < 4; ++m)
                dst[m] = __builtin_amdgcn_mfma_f32_32x32x16_bf16(af[m], bfr, dst[m], 0, 0, 0);
            __builtin_amdgcn_s_setprio(0);
            if (kt < 7) {
                #pragma unroll
                for (int m = 0; m < 4; ++m) af[m] = afn[m];
            }
        }
        if (do_relu) {
            #pragma unroll
            for (int m = 0; m < 4; ++m)
                #pragma unroll
                for (int r = 0; r < 16; ++r)
                    dst[m][r] = fmaxf(dst[m][r], 0.f);
        }
    };

    // prefetch iter-0 obs
    f32x4 pu0, pu1;
    {
        const float* s0 = &obs[(size_t)(blockIdx.x * (8 * ITERS) + wv) * 576 + 32 + l31 * 16 + hi * 8];
        pu0 = *(const f32x4*)s0;
        pu1 = *(const f32x4*)(s0 + 4);
    }

    for (int g = 0; g < ITERS; ++g) {
        const int row0 = blockIdx.x * (8 * ITERS) + g * 8;
        const int rb   = row0 + wv;        // this wave's batch row
        const int xrow = wv * 32;          // its obj-row band in sX

        f32x16 acc1[4], acc2[4];
        float mk, rden;

        // ---- L1: feats (prefetched) as B-operand; bias folded via k=15 ----
        {
            f32x4 u0 = pu0, u1 = pu1;
            float maskv = 0.f;
            if (hi) { maskv = u1.w; u1.w = 1.0f; }   // feature15 = mask -> bias channel
            bf16x8 bfr;
            bfr[0] = (__bf16)u0.x; bfr[1] = (__bf16)u0.y;
            bfr[2] = (__bf16)u0.z; bfr[3] = (__bf16)u0.w;
            bfr[4] = (__bf16)u1.x; bfr[5] = (__bf16)u1.y;
            bfr[6] = (__bf16)u1.z; bfr[7] = (__bf16)u1.w;
            float ma = maskv, mb = maskv;
            pl32swapf(ma, mb);
            mk = hi ? maskv : mb;
            float s = mk;
            s += __shfl_xor(s, 1);  s += __shfl_xor(s, 2);
            s += __shfl_xor(s, 4);  s += __shfl_xor(s, 8);
            s += __shfl_xor(s, 16);
            rden = 1.f / (s + 1e-5f);

            f32x16 z;
            #pragma unroll
            for (int r = 0; r < 16; ++r) z[r] = 0.f;
            __builtin_amdgcn_s_setprio(1);
            #pragma unroll
            for (int m = 0; m < 4; ++m)
                acc1[m] = __builtin_amdgcn_mfma_f32_32x32x16_bf16(w1f[m], bfr, z, 0, 0, 0);
            __builtin_amdgcn_s_setprio(0);

            // prefetch next iter's obs while L1/L2 run
            if (g + 1 < ITERS) {
                const float* sn = &obs[(size_t)(rb + 8) * 576 + 32 + l31 * 16 + hi * 8];
                pu0 = *(const f32x4*)sn;
                pu1 = *(const f32x4*)(sn + 4);
            }
            #pragma unroll
            for (int m = 0; m < 4; ++m)
                #pragma unroll
                for (int r = 0; r < 16; ++r)
                    acc1[m][r] = fmaxf(acc1[m][r], 0.f);
        }

        // ---- L2, L3 ----
        layer32(acc1, acc2, sW2, sB2, true);
        layer32(acc2, acc1, sW3, sB3, false);

        // ---- mask multiply -> x_real in acc1 (vector splat) ----
        #pragma unroll
        for (int m = 0; m < 4; ++m) acc1[m] = acc1[m] * mk;

        // ---- write x_real to sX (wave-private rows; b64 packed, XOR-swizzled) ----
        #pragma unroll
        for (int m = 0; m < 4; ++m)
            #pragma unroll
            for (int rg = 0; rg < 4; ++rg) {
                int pk0 = cvt_pk_bf16(acc1[m][rg * 4 + 0], acc1[m][rg * 4 + 1]);
                int pk1 = cvt_pk_bf16(acc1[m][rg * 4 + 2], acc1[m][rg * 4 + 3]);
                int e0 = m * 32 + rg * 8 + hi * 4;
                int row = xrow + l31;
                int2 pp; pp.x = pk0; pp.y = pk1;
                *(int2*)&sX[row * 128 + (e0 ^ ((row & 7) << 3))] = pp;
            }

        // ---- wave-local colsum -> q (4-way partials) ; aux passthrough ----
        {
            float s0p[4] = {0.f, 0.f, 0.f, 0.f}, s1p[4] = {0.f, 0.f, 0.f, 0.f};
            #pragma unroll
            for (int i = 0; i < 32; ++i) {
                int row = xrow + i;
                unsigned u = *(const unsigned*)&sX[row * 128 + ((2 * lane) ^ ((i & 7) << 3))];
                s0p[i & 3] += bflo(u);
                s1p[i & 3] += bfhi(u);
            }
            float s0 = (s0p[0] + s0p[1]) + (s0p[2] + s0p[3]);
            float s1 = (s1p[0] + s1p[1]) + (s1p[2] + s1p[3]);
            int qpk = cvt_pk_bf16(s0 * rden, s1 * rden);
            *(unsigned*)&sQ[wv * 128 + ((2 * lane) ^ (wv << 3))] = (unsigned)qpk;
            float av = (lane < 32) ? obs[(size_t)rb * 576 + lane]
                                   : obs[(size_t)rb * 576 + 512 + lane];
            out[(size_t)rb * 192 + lane] = av;
        }
        __syncthreads();   // B1: sQ ready for all waves

        // ---- G: v[row][d] = sum_f M[d][f] q[row][f] ----
        {
            f32x4 vac = {0.f, 0.f, 0.f, 0.f};
            __builtin_amdgcn_s_setprio(1);
            #pragma unroll
            for (int kk = 0; kk < 4; ++kk) {
                bf16x8 a = *(const bf16x8*)&sQ[l15 * 128 + ((kk * 32 + kh * 8) ^ ((l15 & 7) << 3))];
                vac = __builtin_amdgcn_mfma_f32_16x16x32_bf16(a, mf[kk], vac, 0, 0, 0);
            }
            __builtin_amdgcn_s_setprio(0);
            if (kh < 2) {
                #pragma unroll
                for (int r = 0; r < 4; ++r)
                    sV[(kh * 4 + r) * 128 + wv * 16 + l15] = vac[r];
            }
        }
        __syncthreads();   // B2: sV ready

        // ---- logits (register x, per-m partials), wave-local softmax, out_att ----
        {
            float lpm[4] = {0.f, 0.f, 0.f, 0.f};
            #pragma unroll
            for (int m = 0; m < 4; ++m)
                #pragma unroll
                for (int rg = 0; rg < 4; ++rg) {
                    f32x4 vv = *(const f32x4*)&sV[wv * 128 + m * 32 + rg * 8 + hi * 4];
                    #pragma unroll
                    for (int r = 0; r < 4; ++r)
                        lpm[m] = fmaf(vv[r], acc1[m][rg * 4 + r], lpm[m]);
                }
            float lp = (lpm[0] + lpm[1]) + (lpm[2] + lpm[3]);
            float la = lp, lb = lp;
            pl32swapf(la, lb);
            float lpo = hi ? la : lb;
            float logit = lp + lpo + (1.f - mk) * (-1e9f);
            float mx = logit;
            mx = fmaxf(mx, __shfl_xor(mx, 1));  mx = fmaxf(mx, __shfl_xor(mx, 2));
            mx = fmaxf(mx, __shfl_xor(mx, 4));  mx = fmaxf(mx, __shfl_xor(mx, 8));
            mx = fmaxf(mx, __shfl_xor(mx, 16));
            float ex = __expf(logit - mx);
            float ss = ex;
            ss += __shfl_xor(ss, 1);  ss += __shfl_xor(ss, 2);
            ss += __shfl_xor(ss, 4);  ss += __shfl_xor(ss, 8);
            ss += __shfl_xor(ss, 16);
            float w = ex / ss;

            float o0p[2] = {0.f, 0.f}, o1p[2] = {0.f, 0.f};
            int wb = __builtin_bit_cast(int, w);
            #pragma unroll
            for (int i = 0; i < 32; ++i) {
                float wi = __builtin_bit_cast(float, __builtin_amdgcn_readlane(wb, i));
                int row = xrow + i;
                unsigned u = *(const unsigned*)&sX[row * 128 + ((2 * lane) ^ ((i & 7) << 3))];
                o0p[i & 1] = fmaf(wi, bflo(u), o0p[i & 1]);
                o1p[i & 1] = fmaf(wi, bfhi(u), o1p[i & 1]);
            }
            float2 o; o.x = o0p[0] + o0p[1]; o.y = o1p[0] + o1p[1];
            *(float2*)&out[(size_t)rb * 192 + 64 + 2 * lane] = o;
        }
        // no end barrier: B1/B2 of next iter order sQ/sV reuse; sX is wave-private
    }
}

extern "C" void kernel_launch(void* const* d_in, const int* in_sizes, int n_in,
                              void* d_out, int out_size, void* d_ws, size_t ws_size,
                              hipStream_t stream) {
    const float* obs = (const float*)d_in[0];
    const float* W1  = (const float*)d_in[1];
    const float* b1  = (const float*)d_in[2];
    const float* W2  = (const float*)d_in[3];
    const float* b2  = (const float*)d_in[4];
    const float* W3  = (const float*)d_in[5];
    const float* b3  = (const float*)d_in[6];
    const float* Uq  = (const float*)d_in[7];
    const float* Ur  = (const float*)d_in[8];
    float* out = (float*)d_out;
    unsigned char* ws = (unsigned char*)d_ws;

    pack_kernel<<<dim3(128), dim3(128), 0, stream>>>(W1, b1, W2, W3, Uq, Ur, ws);
    fused_attn_kernel<<<dim3(GRID), dim3(BLOCK), 0, stream>>>(
        obs, b2, b3, ws, out);
}

// Round 8
// 135.450 us; speedup vs baseline: 1.0044x; 1.0044x over previous
//
#include <hip/hip_runtime.h>

typedef __attribute__((ext_vector_type(8))) __bf16 bf16x8;
typedef __attribute__((ext_vector_type(4))) float f32x4;
typedef __attribute__((ext_vector_type(16))) float f32x16;
typedef __attribute__((ext_vector_type(4))) int i32x4;

#define GRID 1024
#define BLOCK 512
#define ITERS 4   // 8 batch rows per iter -> 32 rows per block

__device__ __forceinline__ int swzi(int row, int col) {
    return row * 128 + (col ^ ((row & 7) << 3));
}
__device__ __forceinline__ int cvt_pk_bf16(float lo, float hi) {
    int r; asm("v_cvt_pk_bf16_f32 %0, %1, %2" : "=v"(r) : "v"(lo), "v"(hi)); return r;
}
__device__ __forceinline__ void pl32swap(int& a, int& b) {
    asm("v_permlane32_swap_b32 %0, %1" : "+v"(a), "+v"(b));
}
__device__ __forceinline__ void pl32swapf(float& a, float& b) {
    asm("v_permlane32_swap_b32 %0, %1" : "+v"(a), "+v"(b));
}
__device__ __forceinline__ float bflo(unsigned u) {
    unsigned v = u << 16; return __builtin_bit_cast(float, v);
}
__device__ __forceinline__ float bfhi(unsigned u) {
    unsigned v = u & 0xffff0000u; return __builtin_bit_cast(float, v);
}

// ws layout (bytes):
//   0     : W1p bf16 [128][16]  (k<15: W1, k==15: b1 bias-fold)
//   4096  : W2p bf16 [128][128] swzi-swizzled (row=out e, col=in d)
//   36864 : W3p bf16 [128][128] swzi-swizzled
//   69632 : Mp  bf16 [128][128] row-major, M[d][f] = sum_e Ur[e][d]*Uq[e][f]
__global__ __launch_bounds__(128)
void pack_kernel(const float* __restrict__ W1, const float* __restrict__ b1,
                 const float* __restrict__ W2, const float* __restrict__ W3,
                 const float* __restrict__ Uq, const float* __restrict__ Ur,
                 unsigned char* __restrict__ ws)
{
    __bf16* w1p = (__bf16*)ws;
    __bf16* w2p = (__bf16*)(ws + 4096);
    __bf16* w3p = (__bf16*)(ws + 36864);
    __bf16* mp  = (__bf16*)(ws + 69632);
    const int d = blockIdx.x, t = threadIdx.x;
    if (t < 16) w1p[d * 16 + t] = (__bf16)((t < 15) ? W1[d * 15 + t] : b1[d]);
    w2p[swzi(d, t)] = (__bf16)W2[d * 128 + t];
    w3p[swzi(d, t)] = (__bf16)W3[d * 128 + t];
    float acc = 0.f;
    for (int e = 0; e < 128; ++e)
        acc = fmaf(Ur[e * 128 + d], Uq[e * 128 + t], acc);
    mp[d * 128 + t] = (__bf16)acc;
}

__global__ __launch_bounds__(BLOCK, 2)
void fused_attn_kernel(const float* __restrict__ obs,
                       const float* __restrict__ b2g, const float* __restrict__ b3g,
                       const unsigned char* __restrict__ ws,
                       float* __restrict__ out)
{
    const __bf16* gW1 = (const __bf16*)ws;
    const __bf16* gW2 = (const __bf16*)(ws + 4096);
    const __bf16* gW3 = (const __bf16*)(ws + 36864);
    const __bf16* gM  = (const __bf16*)(ws + 69632);

    __shared__ __align__(16) __bf16 sW2[128 * 128];
    __shared__ __align__(16) __bf16 sW3[128 * 128];
    __shared__ __align__(16) __bf16 sX[256 * 128];   // x_real: 8 rows x 32 objs
    __shared__ __align__(16) __bf16 sQ[16 * 128];    // q padded to 16 rows
    __shared__ __align__(16) float sV[8 * 128];
    __shared__ __align__(16) float sB2[128], sB3[128];

    const int tid = threadIdx.x, lane = tid & 63, wv = tid >> 6;
    const int l31 = lane & 31, hi = lane >> 5;
    const int l15 = lane & 15, kh = lane >> 4;

    // ---- one-time staging ----
    for (int i = tid * 8; i < 128 * 128; i += BLOCK * 8) {
        *(bf16x8*)&sW2[i] = *(const bf16x8*)&gW2[i];
        *(bf16x8*)&sW3[i] = *(const bf16x8*)&gW3[i];
    }
    for (int i = tid; i < 16 * 128; i += BLOCK) sQ[i] = (__bf16)0.f;
    if (tid < 128) { sB2[tid] = b2g[tid]; sB3[tid] = b3g[tid]; }

    bf16x8 w1f[4];
    #pragma unroll
    for (int m = 0; m < 4; ++m)
        w1f[m] = *(const bf16x8*)&gW1[(m * 32 + l31) * 16 + hi * 8];
    bf16x8 mf[4];
    #pragma unroll
    for (int kk = 0; kk < 4; ++kk)
        mf[kk] = *(const bf16x8*)&gM[(wv * 16 + l15) * 128 + kk * 32 + kh * 8];
    __syncthreads();

    // transposed layer via 32x32x16: dst[e][n] = bias[e] + sum_d Ws[e][d]*src[d][n]
    // bias loaded as accumulator init; A-frags double-buffered in regs.
    auto layer32 = [&](const f32x16 (&src)[4], f32x16 (&dst)[4],
                       const __bf16* Ws, const float* sB, bool do_relu) {
        #pragma unroll
        for (int m = 0; m < 4; ++m)
            #pragma unroll
            for (int rg = 0; rg < 4; ++rg) {
                f32x4 bb = *(const f32x4*)&sB[m * 32 + rg * 8 + hi * 4];
                dst[m][rg * 4 + 0] = bb.x; dst[m][rg * 4 + 1] = bb.y;
                dst[m][rg * 4 + 2] = bb.z; dst[m][rg * 4 + 3] = bb.w;
            }
        bf16x8 af[4];
        #pragma unroll
        for (int m = 0; m < 4; ++m) {
            int row = m * 32 + l31;
            af[m] = *(const bf16x8*)&Ws[row * 128 + ((hi * 8) ^ ((row & 7) << 3))];
        }
        #pragma unroll
        for (int kt = 0; kt < 8; ++kt) {
            bf16x8 afn[4];
            if (kt < 7) {
                #pragma unroll
                for (int m = 0; m < 4; ++m) {
                    int row = m * 32 + l31;
                    afn[m] = *(const bf16x8*)&Ws[row * 128 + (((kt + 1) * 16 + hi * 8) ^ ((row & 7) << 3))];
                }
            }
            const int ms = kt >> 1, b0 = (kt & 1) * 8;
            int Pa0 = cvt_pk_bf16(src[ms][b0 + 0], src[ms][b0 + 1]);
            int Pb0 = cvt_pk_bf16(src[ms][b0 + 2], src[ms][b0 + 3]);
            int Pa1 = cvt_pk_bf16(src[ms][b0 + 4], src[ms][b0 + 5]);
            int Pb1 = cvt_pk_bf16(src[ms][b0 + 6], src[ms][b0 + 7]);
            pl32swap(Pa0, Pa1);
            pl32swap(Pb0, Pb1);
            i32x4 wi; wi.x = Pa0; wi.y = Pb0; wi.z = Pa1; wi.w = Pb1;
            bf16x8 bfr = __builtin_bit_cast(bf16x8, wi);
            __builtin_amdgcn_s_setprio(1);
            #pragma unroll
            for (int m = 0; m < 4; ++m)
                dst[m] = __builtin_amdgcn_mfma_f32_32x32x16_bf16(af[m], bfr, dst[m], 0, 0, 0);
            __builtin_amdgcn_s_setprio(0);
            if (kt < 7) {
                #pragma unroll
                for (int m = 0; m < 4; ++m) af[m] = afn[m];
            }
        }
        if (do_relu) {
            #pragma unroll
            for (int m = 0; m < 4; ++m)
                #pragma unroll
                for (int r = 0; r < 16; ++r)
                    dst[m][r] = fmaxf(dst[m][r], 0.f);
        }
    };

    // prefetch iter-0 obs
    f32x4 pu0, pu1;
    {
        const float* s0 = &obs[(size_t)(blockIdx.x * (8 * ITERS) + wv) * 576 + 32 + l31 * 16 + hi * 8];
        pu0 = *(const f32x4*)s0;
        pu1 = *(const f32x4*)(s0 + 4);
    }

    for (int g = 0; g < ITERS; ++g) {
        const int row0 = blockIdx.x * (8 * ITERS) + g * 8;
        const int rb   = row0 + wv;        // this wave's batch row
        const int xrow = wv * 32;          // its obj-row band in sX

        f32x16 acc1[4], acc2[4];
        float mk, rden;

        // ---- L1: feats (prefetched) as B-operand; bias folded via k=15 ----
        {
            f32x4 u0 = pu0, u1 = pu1;
            float maskv = 0.f;
            if (hi) { maskv = u1.w; u1.w = 1.0f; }   // feature15 = mask -> bias channel
            bf16x8 bfr;
            bfr[0] = (__bf16)u0.x; bfr[1] = (__bf16)u0.y;
            bfr[2] = (__bf16)u0.z; bfr[3] = (__bf16)u0.w;
            bfr[4] = (__bf16)u1.x; bfr[5] = (__bf16)u1.y;
            bfr[6] = (__bf16)u1.z; bfr[7] = (__bf16)u1.w;
            float ma = maskv, mb = maskv;
            pl32swapf(ma, mb);
            mk = hi ? maskv : mb;
            float s = mk;
            s += __shfl_xor(s, 1);  s += __shfl_xor(s, 2);
            s += __shfl_xor(s, 4);  s += __shfl_xor(s, 8);
            s += __shfl_xor(s, 16);
            rden = 1.f / (s + 1e-5f);

            f32x16 z;
            #pragma unroll
            for (int r = 0; r < 16; ++r) z[r] = 0.f;
            __builtin_amdgcn_s_setprio(1);
            #pragma unroll
            for (int m = 0; m < 4; ++m)
                acc1[m] = __builtin_amdgcn_mfma_f32_32x32x16_bf16(w1f[m], bfr, z, 0, 0, 0);
            __builtin_amdgcn_s_setprio(0);

            // prefetch next iter's obs while L1/L2 run
            if (g + 1 < ITERS) {
                const float* sn = &obs[(size_t)(rb + 8) * 576 + 32 + l31 * 16 + hi * 8];
                pu0 = *(const f32x4*)sn;
                pu1 = *(const f32x4*)(sn + 4);
            }
            #pragma unroll
            for (int m = 0; m < 4; ++m)
                #pragma unroll
                for (int r = 0; r < 16; ++r)
                    acc1[m][r] = fmaxf(acc1[m][r], 0.f);
        }

        // ---- L2, L3 ----
        layer32(acc1, acc2, sW2, sB2, true);
        layer32(acc2, acc1, sW3, sB3, false);

        // ---- mask multiply -> x_real in acc1 (vector splat) ----
        #pragma unroll
        for (int m = 0; m < 4; ++m) acc1[m] = acc1[m] * mk;

        // ---- write x_real to sX (wave-private rows; b64 packed, XOR-swizzled) ----
        #pragma unroll
        for (int m = 0; m < 4; ++m)
            #pragma unroll
            for (int rg = 0; rg < 4; ++rg) {
                int pk0 = cvt_pk_bf16(acc1[m][rg * 4 + 0], acc1[m][rg * 4 + 1]);
                int pk1 = cvt_pk_bf16(acc1[m][rg * 4 + 2], acc1[m][rg * 4 + 3]);
                int e0 = m * 32 + rg * 8 + hi * 4;
                int row = xrow + l31;
                int2 pp; pp.x = pk0; pp.y = pk1;
                *(int2*)&sX[row * 128 + (e0 ^ ((row & 7) << 3))] = pp;
            }

        // ---- wave-local colsum -> q (4-way partials) ; aux passthrough ----
        {
            float s0p[4] = {0.f, 0.f, 0.f, 0.f}, s1p[4] = {0.f, 0.f, 0.f, 0.f};
            #pragma unroll
            for (int i = 0; i < 32; ++i) {
                int row = xrow + i;
                unsigned u = *(const unsigned*)&sX[row * 128 + ((2 * lane) ^ ((i & 7) << 3))];
                s0p[i & 3] += bflo(u);
                s1p[i & 3] += bfhi(u);
            }
            float s0 = (s0p[0] + s0p[1]) + (s0p[2] + s0p[3]);
            float s1 = (s1p[0] + s1p[1]) + (s1p[2] + s1p[3]);
            int qpk = cvt_pk_bf16(s0 * rden, s1 * rden);
            *(unsigned*)&sQ[wv * 128 + ((2 * lane) ^ (wv << 3))] = (unsigned)qpk;
            float av = (lane < 32) ? obs[(size_t)rb * 576 + lane]
                                   : obs[(size_t)rb * 576 + 512 + lane];
            out[(size_t)rb * 192 + lane] = av;
        }
        __syncthreads();   // B1: sQ ready for all waves

        // ---- G: v[row][d] = sum_f M[d][f] q[row][f] ----
        {
            f32x4 vac = {0.f, 0.f, 0.f, 0.f};
            __builtin_amdgcn_s_setprio(1);
            #pragma unroll
            for (int kk = 0; kk < 4; ++kk) {
                bf16x8 a = *(const bf16x8*)&sQ[l15 * 128 + ((kk * 32 + kh * 8) ^ ((l15 & 7) << 3))];
                vac = __builtin_amdgcn_mfma_f32_16x16x32_bf16(a, mf[kk], vac, 0, 0, 0);
            }
            __builtin_amdgcn_s_setprio(0);
            if (kh < 2) {
                #pragma unroll
                for (int r = 0; r < 4; ++r)
                    sV[(kh * 4 + r) * 128 + wv * 16 + l15] = vac[r];
            }
        }
        __syncthreads();   // B2: sV ready

        // ---- logits (register x, per-m partials), wave-local softmax, out_att ----
        {
            float lpm[4] = {0.f, 0.f, 0.f, 0.f};
            #pragma unroll
            for (int m = 0; m < 4; ++m)
                #pragma unroll
                for (int rg = 0; rg < 4; ++rg) {
                    f32x4 vv = *(const f32x4*)&sV[wv * 128 + m * 32 + rg * 8 + hi * 4];
                    #pragma unroll
                    for (int r = 0; r < 4; ++r)
                        lpm[m] = fmaf(vv[r], acc1[m][rg * 4 + r], lpm[m]);
                }
            float lp = (lpm[0] + lpm[1]) + (lpm[2] + lpm[3]);
            float la = lp, lb = lp;
            pl32swapf(la, lb);
            float lpo = hi ? la : lb;
            float logit = lp + lpo + (1.f - mk) * (-1e9f);
            float mx = logit;
            mx = fmaxf(mx, __shfl_xor(mx, 1));  mx = fmaxf(mx, __shfl_xor(mx, 2));
            mx = fmaxf(mx, __shfl_xor(mx, 4));  mx = fmaxf(mx, __shfl_xor(mx, 8));
            mx = fmaxf(mx, __shfl_xor(mx, 16));
            float ex = __expf(logit - mx);
            float ss = ex;
            ss += __shfl_xor(ss, 1);  ss += __shfl_xor(ss, 2);
            ss += __shfl_xor(ss, 4);  ss += __shfl_xor(ss, 8);
            ss += __shfl_xor(ss, 16);
            float w = ex / ss;

            float o0p[2] = {0.f, 0.f}, o1p[2] = {0.f, 0.f};
            int wb = __builtin_bit_cast(int, w);
            #pragma unroll
            for (int i = 0; i < 32; ++i) {
                float wi = __builtin_bit_cast(float, __builtin_amdgcn_readlane(wb, i));
                int row = xrow + i;
                unsigned u = *(const unsigned*)&sX[row * 128 + ((2 * lane) ^ ((i & 7) << 3))];
                o0p[i & 1] = fmaf(wi, bflo(u), o0p[i & 1]);
                o1p[i & 1] = fmaf(wi, bfhi(u), o1p[i & 1]);
            }
            float2 o; o.x = o0p[0] + o0p[1]; o.y = o1p[0] + o1p[1];
            *(float2*)&out[(size_t)rb * 192 + 64 + 2 * lane] = o;
        }
        // no end barrier: B1/B2 of next iter order sQ/sV reuse; sX is wave-private
    }
}

extern "C" void kernel_launch(void* const* d_in, const int* in_sizes, int n_in,
                              void* d_out, int out_size, void* d_ws, size_t ws_size,
                              hipStream_t stream) {
    const float* obs = (const float*)d_in[0];
    const float* W1  = (const float*)d_in[1];
    const float* b1  = (const float*)d_in[2];
    const float* W2  = (const float*)d_in[3];
    const float* b2  = (const float*)d_in[4];
    const float* W3  = (const float*)d_in[5];
    const float* b3  = (const float*)d_in[6];
    const float* Uq  = (const float*)d_in[7];
    const float* Ur  = (const float*)d_in[8];
    float* out = (float*)d_out;
    unsigned char* ws = (unsigned char*)d_ws;

    pack_kernel<<<dim3(128), dim3(128), 0, stream>>>(W1, b1, W2, W3, Uq, Ur, ws);
    fused_attn_kernel<<<dim3(GRID), dim3(BLOCK), 0, stream>>>(
        obs, b2, b3, ws, out);
}

// Round 9
// 108.941 us; speedup vs baseline: 1.2488x; 1.2433x over previous
//
#include <hip/hip_runtime.h>

typedef __attribute__((ext_vector_type(8))) __bf16 bf16x8;
typedef __attribute__((ext_vector_type(4))) float f32x4;
typedef __attribute__((ext_vector_type(16))) float f32x16;
typedef __attribute__((ext_vector_type(4))) int i32x4;

#define GRID 1024
#define BLOCK 512
#define ITERS 4   // 8 batch rows per iter -> 32 rows per block

__device__ __forceinline__ int swzi(int row, int col) {
    return row * 128 + (col ^ ((row & 7) << 3));
}
__device__ __forceinline__ int cvt_pk_bf16(float lo, float hi) {
    int r; asm("v_cvt_pk_bf16_f32 %0, %1, %2" : "=v"(r) : "v"(lo), "v"(hi)); return r;
}
__device__ __forceinline__ void pl32swap(int& a, int& b) {
    asm("v_permlane32_swap_b32 %0, %1" : "+v"(a), "+v"(b));
}
__device__ __forceinline__ void pl32swapf(float& a, float& b) {
    asm("v_permlane32_swap_b32 %0, %1" : "+v"(a), "+v"(b));
}
__device__ __forceinline__ float bflo(unsigned u) {
    unsigned v = u << 16; return __builtin_bit_cast(float, v);
}
__device__ __forceinline__ float bfhi(unsigned u) {
    unsigned v = u & 0xffff0000u; return __builtin_bit_cast(float, v);
}

// ws layout (bytes):
//   0     : W1p bf16 [128][16]  (k<15: W1, k==15: b1 bias-fold)
//   4096  : W2p bf16 [128][128] swzi-swizzled (row=out e, col=in d)
//   36864 : W3p bf16 [128][128] swzi-swizzled
//   69632 : Mp  bf16 [128][128] row-major, M[d][f] = sum_e Ur[e][d]*Uq[e][f]
__global__ __launch_bounds__(128)
void pack_kernel(const float* __restrict__ W1, const float* __restrict__ b1,
                 const float* __restrict__ W2, const float* __restrict__ W3,
                 const float* __restrict__ Uq, const float* __restrict__ Ur,
                 unsigned char* __restrict__ ws)
{
    __bf16* w1p = (__bf16*)ws;
    __bf16* w2p = (__bf16*)(ws + 4096);
    __bf16* w3p = (__bf16*)(ws + 36864);
    __bf16* mp  = (__bf16*)(ws + 69632);
    const int d = blockIdx.x, t = threadIdx.x;
    if (t < 16) w1p[d * 16 + t] = (__bf16)((t < 15) ? W1[d * 15 + t] : b1[d]);
    w2p[swzi(d, t)] = (__bf16)W2[d * 128 + t];
    w3p[swzi(d, t)] = (__bf16)W3[d * 128 + t];
    float acc = 0.f;
    for (int e = 0; e < 128; ++e)
        acc = fmaf(Ur[e * 128 + d], Uq[e * 128 + t], acc);
    mp[d * 128 + t] = (__bf16)acc;
}

__global__ __launch_bounds__(BLOCK, 2)
void fused_attn_kernel(const float* __restrict__ obs,
                       const float* __restrict__ b2g, const float* __restrict__ b3g,
                       const unsigned char* __restrict__ ws,
                       float* __restrict__ out)
{
    const __bf16* gW1 = (const __bf16*)ws;
    const __bf16* gW2 = (const __bf16*)(ws + 4096);
    const __bf16* gW3 = (const __bf16*)(ws + 36864);
    const __bf16* gM  = (const __bf16*)(ws + 69632);

    __shared__ __align__(16) __bf16 sW2[128 * 128];
    __shared__ __align__(16) __bf16 sW3[128 * 128];
    __shared__ __align__(16) __bf16 sX[256 * 128];   // x_real: 8 rows x 32 objs
    __shared__ __align__(16) __bf16 sQ[16 * 128];    // q padded to 16 rows
    __shared__ __align__(16) float sV[8 * 128];
    __shared__ __align__(16) float sB2[128], sB3[128];

    const int tid = threadIdx.x, lane = tid & 63, wv = tid >> 6;
    const int l31 = lane & 31, hi = lane >> 5;
    const int l15 = lane & 15, kh = lane >> 4;

    // ---- one-time staging ----
    for (int i = tid * 8; i < 128 * 128; i += BLOCK * 8) {
        *(bf16x8*)&sW2[i] = *(const bf16x8*)&gW2[i];
        *(bf16x8*)&sW3[i] = *(const bf16x8*)&gW3[i];
    }
    for (int i = tid; i < 16 * 128; i += BLOCK) sQ[i] = (__bf16)0.f;
    if (tid < 128) { sB2[tid] = b2g[tid]; sB3[tid] = b3g[tid]; }

    bf16x8 w1f[4];
    #pragma unroll
    for (int m = 0; m < 4; ++m)
        w1f[m] = *(const bf16x8*)&gW1[(m * 32 + l31) * 16 + hi * 8];
    bf16x8 mf[4];
    #pragma unroll
    for (int kk = 0; kk < 4; ++kk)
        mf[kk] = *(const bf16x8*)&gM[(wv * 16 + l15) * 128 + kk * 32 + kh * 8];
    __syncthreads();

    // transposed layer via 32x32x16: dst[e][n] = bias[e] + sum_d Ws[e][d]*src[d][n]
    // bias is loaded as the accumulator init (saves the epilogue adds).
    auto layer32 = [&](const f32x16 (&src)[4], f32x16 (&dst)[4],
                       const __bf16* Ws, const float* sB, bool do_relu) {
        #pragma unroll
        for (int m = 0; m < 4; ++m)
            #pragma unroll
            for (int rg = 0; rg < 4; ++rg) {
                f32x4 bb = *(const f32x4*)&sB[m * 32 + rg * 8 + hi * 4];
                dst[m][rg * 4 + 0] = bb.x; dst[m][rg * 4 + 1] = bb.y;
                dst[m][rg * 4 + 2] = bb.z; dst[m][rg * 4 + 3] = bb.w;
            }
        #pragma unroll
        for (int kt = 0; kt < 8; ++kt) {
            const int ms = kt >> 1, b0 = (kt & 1) * 8;
            int Pa0 = cvt_pk_bf16(src[ms][b0 + 0], src[ms][b0 + 1]);
            int Pb0 = cvt_pk_bf16(src[ms][b0 + 2], src[ms][b0 + 3]);
            int Pa1 = cvt_pk_bf16(src[ms][b0 + 4], src[ms][b0 + 5]);
            int Pb1 = cvt_pk_bf16(src[ms][b0 + 6], src[ms][b0 + 7]);
            pl32swap(Pa0, Pa1);   // after: Pa0 = j0,1 word ; Pa1 = j4,5 word (all lanes)
            pl32swap(Pb0, Pb1);   // after: Pb0 = j2,3 word ; Pb1 = j6,7 word
            i32x4 wi; wi.x = Pa0; wi.y = Pb0; wi.z = Pa1; wi.w = Pb1;
            bf16x8 bfr = __builtin_bit_cast(bf16x8, wi);
            #pragma unroll
            for (int m = 0; m < 4; ++m) {
                int row = m * 32 + l31;
                bf16x8 afr = *(const bf16x8*)&Ws[row * 128 + ((kt * 16 + hi * 8) ^ ((row & 7) << 3))];
                dst[m] = __builtin_amdgcn_mfma_f32_32x32x16_bf16(afr, bfr, dst[m], 0, 0, 0);
            }
        }
        if (do_relu) {
            #pragma unroll
            for (int m = 0; m < 4; ++m)
                #pragma unroll
                for (int r = 0; r < 16; ++r)
                    dst[m][r] = fmaxf(dst[m][r], 0.f);
        }
    };

    for (int g = 0; g < ITERS; ++g) {
        const int row0 = blockIdx.x * (8 * ITERS) + g * 8;
        const int rb   = row0 + wv;        // this wave's batch row
        const int xrow = wv * 32;          // its obj-row band in sX

        f32x16 acc1[4], acc2[4];
        float mk, rden;

        // ---- L1: feats direct from global as B-operand; bias folded via k=15 ----
        {
            const float* src = &obs[(size_t)rb * 576 + 32 + l31 * 16 + hi * 8];
            f32x4 u0 = *(const f32x4*)src;
            f32x4 u1 = *(const f32x4*)(src + 4);
            float maskv = 0.f;
            if (hi) { maskv = u1.w; u1.w = 1.0f; }   // feature15 = mask -> bias channel
            bf16x8 bfr;
            bfr[0] = (__bf16)u0.x; bfr[1] = (__bf16)u0.y;
            bfr[2] = (__bf16)u0.z; bfr[3] = (__bf16)u0.w;
            bfr[4] = (__bf16)u1.x; bfr[5] = (__bf16)u1.y;
            bfr[6] = (__bf16)u1.z; bfr[7] = (__bf16)u1.w;
            float ma = maskv, mb = maskv;
            pl32swapf(ma, mb);
            mk = hi ? maskv : mb;
            float s = mk;
            s += __shfl_xor(s, 1);  s += __shfl_xor(s, 2);
            s += __shfl_xor(s, 4);  s += __shfl_xor(s, 8);
            s += __shfl_xor(s, 16);
            rden = 1.f / (s + 1e-5f);

            #pragma unroll
            for (int m = 0; m < 4; ++m) {
                f32x16 z;
                #pragma unroll
                for (int r = 0; r < 16; ++r) z[r] = 0.f;
                acc1[m] = __builtin_amdgcn_mfma_f32_32x32x16_bf16(w1f[m], bfr, z, 0, 0, 0);
                #pragma unroll
                for (int r = 0; r < 16; ++r) acc1[m][r] = fmaxf(acc1[m][r], 0.f);
            }
        }

        // ---- L2, L3 ----
        layer32(acc1, acc2, sW2, sB2, true);
        layer32(acc2, acc1, sW3, sB3, false);

        // ---- mask multiply -> x_real in acc1 ----
        #pragma unroll
        for (int m = 0; m < 4; ++m)
            #pragma unroll
            for (int r = 0; r < 16; ++r) acc1[m][r] *= mk;

        // ---- write x_real to sX (wave-private rows; b64 packed, XOR-swizzled) ----
        #pragma unroll
        for (int m = 0; m < 4; ++m)
            #pragma unroll
            for (int rg = 0; rg < 4; ++rg) {
                int pk0 = cvt_pk_bf16(acc1[m][rg * 4 + 0], acc1[m][rg * 4 + 1]);
                int pk1 = cvt_pk_bf16(acc1[m][rg * 4 + 2], acc1[m][rg * 4 + 3]);
                int e0 = m * 32 + rg * 8 + hi * 4;
                int row = xrow + l31;
                int2 pp; pp.x = pk0; pp.y = pk1;
                *(int2*)&sX[row * 128 + (e0 ^ ((row & 7) << 3))] = pp;
            }

        // ---- wave-local colsum -> q (4-way partials) ; aux passthrough ----
        {
            float s0p[4] = {0.f, 0.f, 0.f, 0.f}, s1p[4] = {0.f, 0.f, 0.f, 0.f};
            #pragma unroll
            for (int i = 0; i < 32; ++i) {
                int row = xrow + i;
                unsigned u = *(const unsigned*)&sX[row * 128 + ((2 * lane) ^ ((i & 7) << 3))];
                s0p[i & 3] += bflo(u);
                s1p[i & 3] += bfhi(u);
            }
            float s0 = (s0p[0] + s0p[1]) + (s0p[2] + s0p[3]);
            float s1 = (s1p[0] + s1p[1]) + (s1p[2] + s1p[3]);
            int qpk = cvt_pk_bf16(s0 * rden, s1 * rden);
            *(unsigned*)&sQ[wv * 128 + ((2 * lane) ^ (wv << 3))] = (unsigned)qpk;
            float av = (lane < 32) ? obs[(size_t)rb * 576 + lane]
                                   : obs[(size_t)rb * 576 + 512 + lane];
            out[(size_t)rb * 192 + lane] = av;
        }
        __syncthreads();   // B1: sQ ready for all waves

        // ---- G: v[row][d] = sum_f M[d][f] q[row][f] (each wave: 16-d slice, all rows) ----
        {
            f32x4 vac = {0.f, 0.f, 0.f, 0.f};
            #pragma unroll
            for (int kk = 0; kk < 4; ++kk) {
                bf16x8 a = *(const bf16x8*)&sQ[l15 * 128 + ((kk * 32 + kh * 8) ^ ((l15 & 7) << 3))];
                vac = __builtin_amdgcn_mfma_f32_16x16x32_bf16(a, mf[kk], vac, 0, 0, 0);
            }
            if (kh < 2) {
                #pragma unroll
                for (int r = 0; r < 4; ++r)
                    sV[(kh * 4 + r) * 128 + wv * 16 + l15] = vac[r];
            }
        }
        __syncthreads();   // B2: sV ready

        // ---- logits (register x, per-m partials), wave-local softmax, out_att ----
        {
            float lpm[4] = {0.f, 0.f, 0.f, 0.f};
            #pragma unroll
            for (int m = 0; m < 4; ++m)
                #pragma unroll
                for (int rg = 0; rg < 4; ++rg) {
                    f32x4 vv = *(const f32x4*)&sV[wv * 128 + m * 32 + rg * 8 + hi * 4];
                    #pragma unroll
                    for (int r = 0; r < 4; ++r)
                        lpm[m] = fmaf(vv[r], acc1[m][rg * 4 + r], lpm[m]);
                }
            float lp = (lpm[0] + lpm[1]) + (lpm[2] + lpm[3]);
            float la = lp, lb = lp;
            pl32swapf(la, lb);
            float lpo = hi ? la : lb;
            float logit = lp + lpo + (1.f - mk) * (-1e9f);
            float mx = logit;
            mx = fmaxf(mx, __shfl_xor(mx, 1));  mx = fmaxf(mx, __shfl_xor(mx, 2));
            mx = fmaxf(mx, __shfl_xor(mx, 4));  mx = fmaxf(mx, __shfl_xor(mx, 8));
            mx = fmaxf(mx, __shfl_xor(mx, 16));
            float ex = __expf(logit - mx);
            float ss = ex;
            ss += __shfl_xor(ss, 1);  ss += __shfl_xor(ss, 2);
            ss += __shfl_xor(ss, 4);  ss += __shfl_xor(ss, 8);
            ss += __shfl_xor(ss, 16);
            float w = ex / ss;

            float o0p[2] = {0.f, 0.f}, o1p[2] = {0.f, 0.f};
            int wb = __builtin_bit_cast(int, w);
            #pragma unroll
            for (int i = 0; i < 32; ++i) {
                float wi = __builtin_bit_cast(float, __builtin_amdgcn_readlane(wb, i));
                int row = xrow + i;
                unsigned u = *(const unsigned*)&sX[row * 128 + ((2 * lane) ^ ((i & 7) << 3))];
                o0p[i & 1] = fmaf(wi, bflo(u), o0p[i & 1]);
                o1p[i & 1] = fmaf(wi, bfhi(u), o1p[i & 1]);
            }
            float2 o; o.x = o0p[0] + o0p[1]; o.y = o1p[0] + o1p[1];
            *(float2*)&out[(size_t)rb * 192 + 64 + 2 * lane] = o;
        }
        // no end barrier: B1/B2 of next iter order sQ/sV reuse; sX is wave-private
    }
}

extern "C" void kernel_launch(void* const* d_in, const int* in_sizes, int n_in,
                              void* d_out, int out_size, void* d_ws, size_t ws_size,
                              hipStream_t stream) {
    const float* obs = (const float*)d_in[0];
    const float* W1  = (const float*)d_in[1];
    const float* b1  = (const float*)d_in[2];
    const float* W2  = (const float*)d_in[3];
    const float* b2  = (const float*)d_in[4];
    const float* W3  = (const float*)d_in[5];
    const float* b3  = (const float*)d_in[6];
    const float* Uq  = (const float*)d_in[7];
    const float* Ur  = (const float*)d_in[8];
    float* out = (float*)d_out;
    unsigned char* ws = (unsigned char*)d_ws;

    pack_kernel<<<dim3(128), dim3(128), 0, stream>>>(W1, b1, W2, W3, Uq, Ur, ws);
    fused_attn_kernel<<<dim3(GRID), dim3(BLOCK), 0, stream>>>(
        obs, b2, b3, ws, out);
}

// Round 11
// 107.108 us; speedup vs baseline: 1.2701x; 1.0171x over previous
//
#include <hip/hip_runtime.h>

typedef __attribute__((ext_vector_type(8))) __bf16 bf16x8;
typedef __attribute__((ext_vector_type(4))) float f32x4;
typedef __attribute__((ext_vector_type(16))) float f32x16;
typedef __attribute__((ext_vector_type(4))) int i32x4;

#define GRID 1024
#define BLOCK 512
#define ITERS 4   // 8 batch rows per iter -> 32 rows per block

// W2/W3 swizzle: XOR 8-elem chunk index with row&15.
// (&7 aliased lanes 8 apart on the same 16B slot -> 4-way conflict on the
//  A-frag ds_read_b128; &15 leaves only 16-apart aliases -> 2-way = free, m136)
__device__ __forceinline__ int swzi(int row, int col) {
    return row * 128 + (col ^ ((row & 15) << 3));
}
__device__ __forceinline__ int cvt_pk_bf16(float lo, float hi) {
    int r; asm("v_cvt_pk_bf16_f32 %0, %1, %2" : "=v"(r) : "v"(lo), "v"(hi)); return r;
}
__device__ __forceinline__ void pl32swap(int& a, int& b) {
    asm("v_permlane32_swap_b32 %0, %1" : "+v"(a), "+v"(b));
}
__device__ __forceinline__ void pl32swapf(float& a, float& b) {
    asm("v_permlane32_swap_b32 %0, %1" : "+v"(a), "+v"(b));
}
__device__ __forceinline__ float bflo(unsigned u) {
    unsigned v = u << 16; return __builtin_bit_cast(float, v);
}
__device__ __forceinline__ float bfhi(unsigned u) {
    unsigned v = u & 0xffff0000u; return __builtin_bit_cast(float, v);
}

// ws layout (bytes):
//   0     : W1p bf16 [128][16]  (k<15: W1, k==15: b1 bias-fold)
//   4096  : W2p bf16 [128][128] swzi-swizzled (row=out e, col=in d)
//   36864 : W3p bf16 [128][128] swzi-swizzled
//   69632 : Mp  bf16 [128][128] row-major, M[d][f] = sum_e Ur[e][d]*Uq[e][f]
__global__ __launch_bounds__(128)
void pack_kernel(const float* __restrict__ W1, const float* __restrict__ b1,
                 const float* __restrict__ W2, const float* __restrict__ W3,
                 const float* __restrict__ Uq, const float* __restrict__ Ur,
                 unsigned char* __restrict__ ws)
{
    __bf16* w1p = (__bf16*)ws;
    __bf16* w2p = (__bf16*)(ws + 4096);
    __bf16* w3p = (__bf16*)(ws + 36864);
    __bf16* mp  = (__bf16*)(ws + 69632);
    const int d = blockIdx.x, t = threadIdx.x;
    if (t < 16) w1p[d * 16 + t] = (__bf16)((t < 15) ? W1[d * 15 + t] : b1[d]);
    w2p[swzi(d, t)] = (__bf16)W2[d * 128 + t];
    w3p[swzi(d, t)] = (__bf16)W3[d * 128 + t];
    float acc = 0.f;
    for (int e = 0; e < 128; ++e)
        acc = fmaf(Ur[e * 128 + d], Uq[e * 128 + t], acc);
    mp[d * 128 + t] = (__bf16)acc;
}

__global__ __launch_bounds__(BLOCK, 2)
void fused_attn_kernel(const float* __restrict__ obs,
                       const float* __restrict__ b2g, const float* __restrict__ b3g,
                       const unsigned char* __restrict__ ws,
                       float* __restrict__ out)
{
    const __bf16* gW1 = (const __bf16*)ws;
    const __bf16* gW2 = (const __bf16*)(ws + 4096);
    const __bf16* gW3 = (const __bf16*)(ws + 36864);
    const __bf16* gM  = (const __bf16*)(ws + 69632);

    __shared__ __align__(16) __bf16 sW2[128 * 128];
    __shared__ __align__(16) __bf16 sW3[128 * 128];
    __shared__ __align__(16) __bf16 sX[256 * 128];   // x_real: 8 rows x 32 objs
    __shared__ __align__(16) __bf16 sQ[16 * 128];    // q padded to 16 rows
    __shared__ __align__(16) float sV[8 * 128];
    __shared__ __align__(16) float sB2[128], sB3[128];

    const int tid = threadIdx.x, lane = tid & 63, wv = tid >> 6;
    const int l31 = lane & 31, hi = lane >> 5;
    const int l15 = lane & 15, kh = lane >> 4;

    // ---- one-time staging ----
    for (int i = tid * 8; i < 128 * 128; i += BLOCK * 8) {
        *(bf16x8*)&sW2[i] = *(const bf16x8*)&gW2[i];
        *(bf16x8*)&sW3[i] = *(const bf16x8*)&gW3[i];
    }
    for (int i = tid; i < 16 * 128; i += BLOCK) sQ[i] = (__bf16)0.f;
    if (tid < 128) { sB2[tid] = b2g[tid]; sB3[tid] = b3g[tid]; }

    bf16x8 w1f[4];
    #pragma unroll
    for (int m = 0; m < 4; ++m)
        w1f[m] = *(const bf16x8*)&gW1[(m * 32 + l31) * 16 + hi * 8];
    bf16x8 mf[4];
    #pragma unroll
    for (int kk = 0; kk < 4; ++kk)
        mf[kk] = *(const bf16x8*)&gM[(wv * 16 + l15) * 128 + kk * 32 + kh * 8];
    __syncthreads();

    // transposed layer via 32x32x16: dst[e][n] = bias[e] + sum_d Ws[e][d]*src[d][n]
    // bias is loaded as the accumulator init (saves the epilogue adds).
    auto layer32 = [&](const f32x16 (&src)[4], f32x16 (&dst)[4],
                       const __bf16* Ws, const float* sB, bool do_relu) {
        #pragma unroll
        for (int m = 0; m < 4; ++m)
            #pragma unroll
            for (int rg = 0; rg < 4; ++rg) {
                f32x4 bb = *(const f32x4*)&sB[m * 32 + rg * 8 + hi * 4];
                dst[m][rg * 4 + 0] = bb.x; dst[m][rg * 4 + 1] = bb.y;
                dst[m][rg * 4 + 2] = bb.z; dst[m][rg * 4 + 3] = bb.w;
            }
        #pragma unroll
        for (int kt = 0; kt < 8; ++kt) {
            const int ms = kt >> 1, b0 = (kt & 1) * 8;
            int Pa0 = cvt_pk_bf16(src[ms][b0 + 0], src[ms][b0 + 1]);
            int Pb0 = cvt_pk_bf16(src[ms][b0 + 2], src[ms][b0 + 3]);
            int Pa1 = cvt_pk_bf16(src[ms][b0 + 4], src[ms][b0 + 5]);
            int Pb1 = cvt_pk_bf16(src[ms][b0 + 6], src[ms][b0 + 7]);
            pl32swap(Pa0, Pa1);   // after: Pa0 = j0,1 word ; Pa1 = j4,5 word (all lanes)
            pl32swap(Pb0, Pb1);   // after: Pb0 = j2,3 word ; Pb1 = j6,7 word
            i32x4 wi; wi.x = Pa0; wi.y = Pb0; wi.z = Pa1; wi.w = Pb1;
            bf16x8 bfr = __builtin_bit_cast(bf16x8, wi);
            #pragma unroll
            for (int m = 0; m < 4; ++m) {
                int row = m * 32 + l31;
                bf16x8 afr = *(const bf16x8*)&Ws[row * 128 + ((kt * 16 + hi * 8) ^ ((row & 15) << 3))];
                dst[m] = __builtin_amdgcn_mfma_f32_32x32x16_bf16(afr, bfr, dst[m], 0, 0, 0);
            }
        }
        if (do_relu) {
            #pragma unroll
            for (int m = 0; m < 4; ++m)
                #pragma unroll
                for (int r = 0; r < 16; ++r)
                    dst[m][r] = fmaxf(dst[m][r], 0.f);
        }
    };

    for (int g = 0; g < ITERS; ++g) {
        const int row0 = blockIdx.x * (8 * ITERS) + g * 8;
        const int rb   = row0 + wv;        // this wave's batch row
        const int xrow = wv * 32;          // its obj-row band in sX

        f32x16 acc1[4], acc2[4];
        float mk, rden;

        // ---- L1: feats direct from global as B-operand; bias folded via k=15 ----
        {
            const float* src = &obs[(size_t)rb * 576 + 32 + l31 * 16 + hi * 8];
            f32x4 u0 = *(const f32x4*)src;
            f32x4 u1 = *(const f32x4*)(src + 4);
            float maskv = 0.f;
            if (hi) { maskv = u1.w; u1.w = 1.0f; }   // feature15 = mask -> bias channel
            bf16x8 bfr;
            bfr[0] = (__bf16)u0.x; bfr[1] = (__bf16)u0.y;
            bfr[2] = (__bf16)u0.z; bfr[3] = (__bf16)u0.w;
            bfr[4] = (__bf16)u1.x; bfr[5] = (__bf16)u1.y;
            bfr[6] = (__bf16)u1.z; bfr[7] = (__bf16)u1.w;
            float ma = maskv, mb = maskv;
            pl32swapf(ma, mb);
            mk = hi ? maskv : mb;
            float s = mk;
            s += __shfl_xor(s, 1);  s += __shfl_xor(s, 2);
            s += __shfl_xor(s, 4);  s += __shfl_xor(s, 8);
            s += __shfl_xor(s, 16);
            rden = 1.f / (s + 1e-5f);

            #pragma unroll
            for (int m = 0; m < 4; ++m) {
                f32x16 z;
                #pragma unroll
                for (int r = 0; r < 16; ++r) z[r] = 0.f;
                acc1[m] = __builtin_amdgcn_mfma_f32_32x32x16_bf16(w1f[m], bfr, z, 0, 0, 0);
                #pragma unroll
                for (int r = 0; r < 16; ++r) acc1[m][r] = fmaxf(acc1[m][r], 0.f);
            }
        }

        // ---- L2, L3 ----
        layer32(acc1, acc2, sW2, sB2, true);
        layer32(acc2, acc1, sW3, sB3, false);

        // ---- mask multiply -> x_real in acc1 ----
        #pragma unroll
        for (int m = 0; m < 4; ++m)
            #pragma unroll
            for (int r = 0; r < 16; ++r) acc1[m][r] *= mk;

        // ---- write x_real to sX (wave-private rows; b64 packed, XOR-swizzled) ----
        #pragma unroll
        for (int m = 0; m < 4; ++m)
            #pragma unroll
            for (int rg = 0; rg < 4; ++rg) {
                int pk0 = cvt_pk_bf16(acc1[m][rg * 4 + 0], acc1[m][rg * 4 + 1]);
                int pk1 = cvt_pk_bf16(acc1[m][rg * 4 + 2], acc1[m][rg * 4 + 3]);
                int e0 = m * 32 + rg * 8 + hi * 4;
                int row = xrow + l31;
                int2 pp; pp.x = pk0; pp.y = pk1;
                *(int2*)&sX[row * 128 + (e0 ^ ((row & 7) << 3))] = pp;
            }

        // ---- wave-local colsum -> q (4-way partials) ; aux passthrough ----
        {
            float s0p[4] = {0.f, 0.f, 0.f, 0.f}, s1p[4] = {0.f, 0.f, 0.f, 0.f};
            #pragma unroll
            for (int i = 0; i < 32; ++i) {
                int row = xrow + i;
                unsigned u = *(const unsigned*)&sX[row * 128 + ((2 * lane) ^ ((i & 7) << 3))];
                s0p[i & 3] += bflo(u);
                s1p[i & 3] += bfhi(u);
            }
            float s0 = (s0p[0] + s0p[1]) + (s0p[2] + s0p[3]);
            float s1 = (s1p[0] + s1p[1]) + (s1p[2] + s1p[3]);
            int qpk = cvt_pk_bf16(s0 * rden, s1 * rden);
            *(unsigned*)&sQ[wv * 128 + ((2 * lane) ^ (wv << 3))] = (unsigned)qpk;
            float av = (lane < 32) ? obs[(size_t)rb * 576 + lane]
                                   : obs[(size_t)rb * 576 + 512 + lane];
            out[(size_t)rb * 192 + lane] = av;
        }
        __syncthreads();   // B1: sQ ready for all waves

        // ---- G: v[row][d] = sum_f M[d][f] q[row][f] (each wave: 16-d slice, all rows) ----
        {
            f32x4 vac = {0.f, 0.f, 0.f, 0.f};
            #pragma unroll
            for (int kk = 0; kk < 4; ++kk) {
                bf16x8 a = *(const bf16x8*)&sQ[l15 * 128 + ((kk * 32 + kh * 8) ^ ((l15 & 7) << 3))];
                vac = __builtin_amdgcn_mfma_f32_16x16x32_bf16(a, mf[kk], vac, 0, 0, 0);
            }
            if (kh < 2) {
                #pragma unroll
                for (int r = 0; r < 4; ++r)
                    sV[(kh * 4 + r) * 128 + wv * 16 + l15] = vac[r];
            }
        }
        __syncthreads();   // B2: sV ready

        // ---- logits (register x, per-m partials), wave-local softmax, out_att ----
        {
            float lpm[4] = {0.f, 0.f, 0.f, 0.f};
            #pragma unroll
            for (int m = 0; m < 4; ++m)
                #pragma unroll
                for (int rg = 0; rg < 4; ++rg) {
                    f32x4 vv = *(const f32x4*)&sV[wv * 128 + m * 32 + rg * 8 + hi * 4];
                    #pragma unroll
                    for (int r = 0; r < 4; ++r)
                        lpm[m] = fmaf(vv[r], acc1[m][rg * 4 + r], lpm[m]);
                }
            float lp = (lpm[0] + lpm[1]) + (lpm[2] + lpm[3]);
            float la = lp, lb = lp;
            pl32swapf(la, lb);
            float lpo = hi ? la : lb;
            float logit = lp + lpo + (1.f - mk) * (-1e9f);
            float mx = logit;
            mx = fmaxf(mx, __shfl_xor(mx, 1));  mx = fmaxf(mx, __shfl_xor(mx, 2));
            mx = fmaxf(mx, __shfl_xor(mx, 4));  mx = fmaxf(mx, __shfl_xor(mx, 8));
            mx = fmaxf(mx, __shfl_xor(mx, 16));
            float ex = __expf(logit - mx);
            float ss = ex;
            ss += __shfl_xor(ss, 1);  ss += __shfl_xor(ss, 2);
            ss += __shfl_xor(ss, 4);  ss += __shfl_xor(ss, 8);
            ss += __shfl_xor(ss, 16);
            float w = ex / ss;

            float o0p[2] = {0.f, 0.f}, o1p[2] = {0.f, 0.f};
            int wb = __builtin_bit_cast(int, w);
            #pragma unroll
            for (int i = 0; i < 32; ++i) {
                float wi = __builtin_bit_cast(float, __builtin_amdgcn_readlane(wb, i));
                int row = xrow + i;
                unsigned u = *(const unsigned*)&sX[row * 128 + ((2 * lane) ^ ((i & 7) << 3))];
                o0p[i & 1] = fmaf(wi, bflo(u), o0p[i & 1]);
                o1p[i & 1] = fmaf(wi, bfhi(u), o1p[i & 1]);
            }
            float2 o; o.x = o0p[0] + o0p[1]; o.y = o1p[0] + o1p[1];
            *(float2*)&out[(size_t)rb * 192 + 64 + 2 * lane] = o;
        }
        // no end barrier: B1/B2 of next iter order sQ/sV reuse; sX is wave-private
    }
}

extern "C" void kernel_launch(void* const* d_in, const int* in_sizes, int n_in,
                              void* d_out, int out_size, void* d_ws, size_t ws_size,
                              hipStream_t stream) {
    const float* obs = (const float*)d_in[0];
    const float* W1  = (const float*)d_in[1];
    const float* b1  = (const float*)d_in[2];
    const float* W2  = (const float*)d_in[3];
    const float* b2  = (const float*)d_in[4];
    const float* W3  = (const float*)d_in[5];
    const float* b3  = (const float*)d_in[6];
    const float* Uq  = (const float*)d_in[7];
    const float* Ur  = (const float*)d_in[8];
    float* out = (float*)d_out;
    unsigned char* ws = (unsigned char*)d_ws;

    pack_kernel<<<dim3(128), dim3(128), 0, stream>>>(W1, b1, W2, W3, Uq, Ur, ws);
    fused_attn_kernel<<<dim3(GRID), dim3(BLOCK), 0, stream>>>(
        obs, b2, b3, ws, out);
}